// Round 4
// baseline (406.075 us; speedup 1.0000x reference)
//
#include <hip/hip_runtime.h>
#include <cmath>

namespace {

constexpr int BATCH = 256;
// layer 1
constexpr int C1 = 3, H1 = 218, W1 = 178;
constexpr int IMG1 = C1 * H1 * W1;            // 116412
constexpr int PLANE1 = H1 * W1;               // 38804
constexpr int O1 = 8, HO1 = 54, WO1 = 44;
constexpr int HW1 = HO1 * WO1;                // 2376
constexpr int P1 = C1 * 36;                   // 108
// layer 2
constexpr int C2 = 8, H2c = 54, W2c = 44;
constexpr int IMG2 = C2 * H2c * W2c;          // 19008
constexpr int PLANE2 = H2c * W2c;             // 2376
constexpr int O2 = 16, HO2 = 13, WO2 = 10;
constexpr int HW2 = HO2 * WO2;                // 130
constexpr int P2 = C2 * 36;                   // 288
// head
constexpr int NPOOL = 480;                    // 16*6*5
constexpr int N1 = 300, N2 = 200;

// lc1 blocking: 4 waves/block, each wave = BJ1 batches; block covers 64 hw.
constexpr int BJ1 = 4;                        // batches per thread
constexpr int BPB1 = 4 * BJ1;                 // batches per block = 16

// ---- transpose w1 (O1,P1,HW1) -> (P1*HW1, O1)
__global__ __launch_bounds__(256) void wt1_kernel(const float* __restrict__ w,
                                                  float* __restrict__ wt) {
  const int idx = blockIdx.x * 256 + threadIdx.x;   // p*HW1 + hw
  if (idx >= P1 * HW1) return;
  float v[O1];
#pragma unroll
  for (int o = 0; o < O1; ++o) v[o] = w[(size_t)o * (P1 * HW1) + idx];
  float4* dst = reinterpret_cast<float4*>(wt + (size_t)idx * O1);
  dst[0] = make_float4(v[0], v[1], v[2], v[3]);
  dst[1] = make_float4(v[4], v[5], v[6], v[7]);
}

// ---- transpose w2 (O2,P2,HW2) -> (P2*HW2, O2)
__global__ __launch_bounds__(256) void wt2_kernel(const float* __restrict__ w,
                                                  float* __restrict__ wt) {
  const int idx = blockIdx.x * 256 + threadIdx.x;   // p*HW2 + hw
  if (idx >= P2 * HW2) return;
  float v[O2];
#pragma unroll
  for (int o = 0; o < O2; ++o) v[o] = w[(size_t)o * (P2 * HW2) + idx];
  float4* dst = reinterpret_cast<float4*>(wt + (size_t)idx * O2);
  dst[0] = make_float4(v[0], v[1], v[2], v[3]);
  dst[1] = make_float4(v[4], v[5], v[6], v[7]);
  dst[2] = make_float4(v[8], v[9], v[10], v[11]);
  dst[3] = make_float4(v[12], v[13], v[14], v[15]);
}

// ---- locally-connected layer 1 + ReLU
// 256 thr = 64 hw-lanes x 4 waves (wave = 4 batches); grid (38, 16).
// __launch_bounds__(256,2): cap VGPR at 128 so the scheduler can keep
// ~20 loads in flight (round-3 had VGPR=32 -> ~4 in flight -> latency-bound
// at VALUBusy 8%). Explicit x ping-pong prefetch hides x latency under the
// 192 FMAs of the current (c,kh) body.
__global__ __launch_bounds__(256, 2) void lc1_kernel(const float* __restrict__ x,
                                                     const float* __restrict__ w1t,
                                                     const float* __restrict__ b1,
                                                     float* __restrict__ h1) {
  const int lane = threadIdx.x & 63;
  const int wave = threadIdx.x >> 6;
  const int hw = blockIdx.x * 64 + lane;
  if (hw >= HW1) return;
  const int bg = blockIdx.y * BPB1 + wave * BJ1;
  const int ho = hw / WO1, wo = hw - ho * WO1;

  float acc[BJ1][O1];
#pragma unroll
  for (int o = 0; o < O1; ++o) {
    const float bv = b1[o * HW1 + hw];
#pragma unroll
    for (int j = 0; j < BJ1; ++j) acc[j][o] = bv;
  }

  const float* xbase = x + (size_t)bg * IMG1 + (size_t)(ho * 4) * W1 + wo * 4;
  const float* wbase = w1t + (size_t)hw * O1;

  float xv[BJ1][6], xn[BJ1][6];

#define LOADX(dst, off)                                                      \
  do {                                                                       \
    _Pragma("unroll") for (int j = 0; j < BJ1; ++j) {                        \
      const float* xr = xbase + (size_t)j * IMG1 + (off);                    \
      const float2 a0 = *reinterpret_cast<const float2*>(xr);                \
      const float2 a1 = *reinterpret_cast<const float2*>(xr + 2);            \
      const float2 a2 = *reinterpret_cast<const float2*>(xr + 4);            \
      dst[j][0] = a0.x; dst[j][1] = a0.y;                                    \
      dst[j][2] = a1.x; dst[j][3] = a1.y;                                    \
      dst[j][4] = a2.x; dst[j][5] = a2.y;                                    \
    }                                                                        \
  } while (0)

  LOADX(xv, 0);  // (c=0, kh=0)

#pragma unroll 1
  for (int c = 0; c < C1; ++c) {
    const size_t coff = (size_t)c * PLANE1;
#pragma unroll
    for (int kh = 0; kh < 6; ++kh) {
      // prefetch next body's x
      if (kh < 5) {
        LOADX(xn, coff + (size_t)(kh + 1) * W1);
      } else if (c < C1 - 1) {
        LOADX(xn, coff + PLANE1);
      }
      const float* wp = wbase + (size_t)((c * 6 + kh) * 6) * (HW1 * O1);
#pragma unroll
      for (int kw = 0; kw < 6; ++kw) {
        const float4 wa = *reinterpret_cast<const float4*>(wp + (size_t)kw * (HW1 * O1));
        const float4 wb = *reinterpret_cast<const float4*>(wp + (size_t)kw * (HW1 * O1) + 4);
#pragma unroll
        for (int j = 0; j < BJ1; ++j) {
          const float xs = xv[j][kw];
          acc[j][0] = fmaf(xs, wa.x, acc[j][0]);
          acc[j][1] = fmaf(xs, wa.y, acc[j][1]);
          acc[j][2] = fmaf(xs, wa.z, acc[j][2]);
          acc[j][3] = fmaf(xs, wa.w, acc[j][3]);
          acc[j][4] = fmaf(xs, wb.x, acc[j][4]);
          acc[j][5] = fmaf(xs, wb.y, acc[j][5]);
          acc[j][6] = fmaf(xs, wb.z, acc[j][6]);
          acc[j][7] = fmaf(xs, wb.w, acc[j][7]);
        }
      }
      // rotate prefetched x into place (renamed away within unrolled kh)
#pragma unroll
      for (int j = 0; j < BJ1; ++j)
#pragma unroll
        for (int k = 0; k < 6; ++k) xv[j][k] = xn[j][k];
    }
  }
#undef LOADX

#pragma unroll
  for (int j = 0; j < BJ1; ++j) {
    float* op = h1 + ((size_t)(bg + j) * O1) * HW1 + hw;
#pragma unroll
    for (int o = 0; o < O1; ++o) op[(size_t)o * HW1] = fmaxf(acc[j][o], 0.f);
  }
}

// ---- locally-connected layer 2 + ReLU, GEMM-ified per spatial location.
__global__ __launch_bounds__(256) void lc2_kernel(const float* __restrict__ h1,
                                                  const float* __restrict__ w2t,
                                                  const float* __restrict__ b2,
                                                  float* __restrict__ h2) {
  __shared__ float ws[P2 * O2];                 // 18432 B
  const int hw = blockIdx.x;
  const int lane = threadIdx.x & 63;
  const int og = threadIdx.x >> 6;
  const int b = blockIdx.y * 64 + lane;
  const int ho = hw / WO2, wo = hw - ho * WO2;

  for (int i = threadIdx.x; i < P2 * O2; i += 256) {
    const int p = i >> 4, o = i & 15;
    ws[i] = w2t[((size_t)p * HW2 + hw) * O2 + o];
  }
  __syncthreads();

  float acc[4];
#pragma unroll
  for (int oi = 0; oi < 4; ++oi) acc[oi] = b2[(og * 4 + oi) * HW2 + hw];

  const float* xb = h1 + (size_t)b * IMG2 + (size_t)(ho * 4) * W2c + wo * 4;

#pragma unroll 1
  for (int c = 0; c < C2; ++c) {
#pragma unroll
    for (int kh = 0; kh < 6; ++kh) {
      const float* xr = xb + c * PLANE2 + kh * W2c;
      const float2 a0 = *reinterpret_cast<const float2*>(xr);
      const float2 a1 = *reinterpret_cast<const float2*>(xr + 2);
      const float2 a2 = *reinterpret_cast<const float2*>(xr + 4);
      float xvv[6];
      xvv[0] = a0.x; xvv[1] = a0.y; xvv[2] = a1.x;
      xvv[3] = a1.y; xvv[4] = a2.x; xvv[5] = a2.y;
#pragma unroll
      for (int kw = 0; kw < 6; ++kw) {
        const int p = (c * 6 + kh) * 6 + kw;
        const float4 wv = *reinterpret_cast<const float4*>(&ws[p * O2 + og * 4]);
        acc[0] = fmaf(xvv[kw], wv.x, acc[0]);
        acc[1] = fmaf(xvv[kw], wv.y, acc[1]);
        acc[2] = fmaf(xvv[kw], wv.z, acc[2]);
        acc[3] = fmaf(xvv[kw], wv.w, acc[3]);
      }
    }
  }

#pragma unroll
  for (int oi = 0; oi < 4; ++oi) {
    h2[((size_t)b * O2 + og * 4 + oi) * HW2 + hw] = fmaxf(acc[oi], 0.f);
  }
}

// ---- fused head: maxpool(2) -> FC1+ReLU -> FC2 -> softmax.
// one block (512 thr = 8 waves) per batch row; all intermediates in LDS.
__global__ __launch_bounds__(512) void head_kernel(const float* __restrict__ h2,
                                                   const float* __restrict__ fc1w,
                                                   const float* __restrict__ fc1b,
                                                   const float* __restrict__ fc2w,
                                                   const float* __restrict__ fc2b,
                                                   float* __restrict__ out) {
  __shared__ __align__(16) float sp[NPOOL];
  __shared__ __align__(16) float sh[N1];
  __shared__ float sl[N2];
  __shared__ float red[2];
  const int b = blockIdx.x;
  const int tid = threadIdx.x;

  if (tid < NPOOL) {
    const int o = tid / 30, r2 = tid - o * 30;
    const int i = r2 / 5, j = r2 - i * 5;
    const float* base = h2 + ((size_t)(b * O2 + o) * HO2 + 2 * i) * WO2 + 2 * j;
    sp[tid] = fmaxf(fmaxf(base[0], base[1]), fmaxf(base[WO2], base[WO2 + 1]));
  }
  __syncthreads();

  const int wv = tid >> 6, ln = tid & 63;
  const float4* sp4 = reinterpret_cast<const float4*>(sp);
  for (int n = wv; n < N1; n += 8) {
    const float4* wr = reinterpret_cast<const float4*>(fc1w + (size_t)n * NPOOL);
    float4 a = wr[ln], p = sp4[ln];
    float s = fmaf(a.x, p.x, fmaf(a.y, p.y, fmaf(a.z, p.z, a.w * p.w)));
    if (ln < 56) {
      float4 a2 = wr[64 + ln], p2 = sp4[64 + ln];
      s = fmaf(a2.x, p2.x, fmaf(a2.y, p2.y, fmaf(a2.z, p2.z, fmaf(a2.w, p2.w, s))));
    }
#pragma unroll
    for (int off = 32; off > 0; off >>= 1) s += __shfl_xor(s, off, 64);
    if (ln == 0) sh[n] = fmaxf(s + fc1b[n], 0.f);
  }
  __syncthreads();

  const float4* sh4 = reinterpret_cast<const float4*>(sh);
  for (int n = wv; n < N2; n += 8) {
    const float4* wr = reinterpret_cast<const float4*>(fc2w + (size_t)n * N1);
    float4 a = wr[ln], p = sh4[ln];
    float s = fmaf(a.x, p.x, fmaf(a.y, p.y, fmaf(a.z, p.z, a.w * p.w)));
    if (ln < 11) {
      float4 a2 = wr[64 + ln], p2 = sh4[64 + ln];
      s = fmaf(a2.x, p2.x, fmaf(a2.y, p2.y, fmaf(a2.z, p2.z, fmaf(a2.w, p2.w, s))));
    }
#pragma unroll
    for (int off = 32; off > 0; off >>= 1) s += __shfl_xor(s, off, 64);
    if (ln == 0) sl[n] = s + fc2b[n];
  }
  __syncthreads();

  if (wv == 0) {
    float m = fmaxf(fmaxf(sl[ln], sl[ln + 64]), sl[ln + 128]);
    if (ln < 8) m = fmaxf(m, sl[192 + ln]);
#pragma unroll
    for (int off = 32; off > 0; off >>= 1) m = fmaxf(m, __shfl_xor(m, off, 64));
    if (ln == 0) red[0] = m;
  }
  __syncthreads();
  const float mx = red[0];
  if (tid < N2) sl[tid] = expf(sl[tid] - mx);
  __syncthreads();
  if (wv == 0) {
    float s = sl[ln] + sl[ln + 64] + sl[ln + 128] + (ln < 8 ? sl[192 + ln] : 0.f);
#pragma unroll
    for (int off = 32; off > 0; off >>= 1) s += __shfl_xor(s, off, 64);
    if (ln == 0) red[1] = s;
  }
  __syncthreads();
  if (tid < N2) out[(size_t)b * N2 + tid] = sl[tid] / red[1];
}

}  // namespace

extern "C" void kernel_launch(void* const* d_in, const int* in_sizes, int n_in,
                              void* d_out, int out_size, void* d_ws, size_t ws_size,
                              hipStream_t stream) {
  const float* x     = (const float*)d_in[0];
  const float* w1    = (const float*)d_in[1];
  const float* b1    = (const float*)d_in[2];
  const float* w2    = (const float*)d_in[3];
  const float* b2    = (const float*)d_in[4];
  const float* fc1_w = (const float*)d_in[5];
  const float* fc1_b = (const float*)d_in[6];
  const float* fc2_w = (const float*)d_in[7];
  const float* fc2_b = (const float*)d_in[8];
  float* out = (float*)d_out;

  float* ws  = (float*)d_ws;
  float* w1t = ws;                                  // 2,052,864 f
  float* w2t = w1t + (size_t)O1 * P1 * HW1;         //   599,040 f
  float* h1  = w2t + (size_t)O2 * P2 * HW2;         // 4,866,048 f
  float* h2  = h1 + (size_t)BATCH * O1 * HW1;       //   532,480 f

  wt1_kernel<<<(P1 * HW1 + 255) / 256, 256, 0, stream>>>(w1, w1t);
  wt2_kernel<<<(P2 * HW2 + 255) / 256, 256, 0, stream>>>(w2, w2t);
  lc1_kernel<<<dim3((HW1 + 63) / 64, BATCH / BPB1), 256, 0, stream>>>(x, w1t, b1, h1);
  lc2_kernel<<<dim3(HW2, 4), 256, 0, stream>>>(h1, w2t, b2, h2);
  head_kernel<<<BATCH, 512, 0, stream>>>(h2, fc1_w, fc1_b, fc2_w, fc2_b, out);
}

// Round 5
// 191.127 us; speedup vs baseline: 2.1246x; 2.1246x over previous
//
#include <hip/hip_runtime.h>
#include <cmath>

namespace {

constexpr int BATCH = 256;
// layer 1
constexpr int C1 = 3, H1 = 218, W1 = 178;
constexpr int IMG1 = C1 * H1 * W1;            // 116412
constexpr int PLANE1 = H1 * W1;               // 38804
constexpr int O1 = 8, HO1 = 54, WO1 = 44;
constexpr int HW1 = HO1 * WO1;                // 2376
constexpr int P1 = C1 * 36;                   // 108
// layer 2
constexpr int C2 = 8, H2c = 54, W2c = 44;
constexpr int IMG2 = C2 * H2c * W2c;          // 19008
constexpr int PLANE2 = H2c * W2c;             // 2376
constexpr int O2 = 16, HO2 = 13, WO2 = 10;
constexpr int HW2 = HO2 * WO2;                // 130
constexpr int P2 = C2 * 36;                   // 288
// head
constexpr int NPOOL = 480;                    // 16*6*5
constexpr int N1 = 300, N2 = 200;

// lc1 blocking: 4 waves/block, each wave = 2 batches; block covers 64 hw.
constexpr int BJ1 = 2;
constexpr int BPB1 = 4 * BJ1;                 // 8 batches per block

// ---- transpose w1 (O1,P1,HW1) -> (P1*HW1, O1)
__global__ __launch_bounds__(256) void wt1_kernel(const float* __restrict__ w,
                                                  float* __restrict__ wt) {
  const int idx = blockIdx.x * 256 + threadIdx.x;   // p*HW1 + hw
  if (idx >= P1 * HW1) return;
  float v[O1];
#pragma unroll
  for (int o = 0; o < O1; ++o) v[o] = w[(size_t)o * (P1 * HW1) + idx];
  float4* dst = reinterpret_cast<float4*>(wt + (size_t)idx * O1);
  dst[0] = make_float4(v[0], v[1], v[2], v[3]);
  dst[1] = make_float4(v[4], v[5], v[6], v[7]);
}

// ---- transpose w2 (O2,P2,HW2) -> (P2*HW2, O2)
__global__ __launch_bounds__(256) void wt2_kernel(const float* __restrict__ w,
                                                  float* __restrict__ wt) {
  const int idx = blockIdx.x * 256 + threadIdx.x;   // p*HW2 + hw
  if (idx >= P2 * HW2) return;
  float v[O2];
#pragma unroll
  for (int o = 0; o < O2; ++o) v[o] = w[(size_t)o * (P2 * HW2) + idx];
  float4* dst = reinterpret_cast<float4*>(wt + (size_t)idx * O2);
  dst[0] = make_float4(v[0], v[1], v[2], v[3]);
  dst[1] = make_float4(v[4], v[5], v[6], v[7]);
  dst[2] = make_float4(v[8], v[9], v[10], v[11]);
  dst[3] = make_float4(v[12], v[13], v[14], v[15]);
}

// ---- locally-connected layer 1 + ReLU
// 256 thr = 64 hw-lanes x 4 waves (wave = 2 batches); grid (38, 32).
// Memory-level-parallelism fix: per (c,kh) body, issue ALL 6 x loads then
// ALL 12 w float4 loads into named registers before any FMA consumes them
// (~18 VMEM in flight vs ~1-2 in rounds 2-3, which measured at 0.7 lines
// outstanding/wave => 1.2 TB/s). Live set ~90 VGPR; no launch_bounds cap,
// no ping-pong rotate (round-4's rotate spilled 394 MB to scratch).
__global__ __launch_bounds__(256) void lc1_kernel(const float* __restrict__ x,
                                                  const float* __restrict__ w1t,
                                                  const float* __restrict__ b1,
                                                  float* __restrict__ h1) {
  const int lane = threadIdx.x & 63;
  const int wave = threadIdx.x >> 6;
  const int hw = blockIdx.x * 64 + lane;
  if (hw >= HW1) return;
  const int bg = blockIdx.y * BPB1 + wave * BJ1;
  const int ho = hw / WO1, wo = hw - ho * WO1;

  float acc[BJ1][O1];
#pragma unroll
  for (int o = 0; o < O1; ++o) {
    const float bv = b1[o * HW1 + hw];
#pragma unroll
    for (int j = 0; j < BJ1; ++j) acc[j][o] = bv;
  }

  const float* xbase = x + (size_t)bg * IMG1 + (size_t)(ho * 4) * W1 + wo * 4;
  const float* wbase = w1t + (size_t)hw * O1;
  constexpr size_t WSTRIDE = (size_t)HW1 * O1;      // floats between consecutive p

#pragma unroll 1
  for (int c = 0; c < C1; ++c) {
#pragma unroll
    for (int kh = 0; kh < 6; ++kh) {
      // ---- issue x loads (6 VMEM, independent)
      float xv[BJ1][6];
#pragma unroll
      for (int j = 0; j < BJ1; ++j) {
        const float* xr = xbase + (size_t)j * IMG1 + (size_t)c * PLANE1 + (size_t)kh * W1;
        const float2 a0 = *reinterpret_cast<const float2*>(xr);
        const float2 a1 = *reinterpret_cast<const float2*>(xr + 2);
        const float2 a2 = *reinterpret_cast<const float2*>(xr + 4);
        xv[j][0] = a0.x; xv[j][1] = a0.y;
        xv[j][2] = a1.x; xv[j][3] = a1.y;
        xv[j][4] = a2.x; xv[j][5] = a2.y;
      }
      // ---- issue ALL 12 w loads for this (c,kh) (independent, named regs)
      const float* wp = wbase + (size_t)((c * 6 + kh) * 6) * WSTRIDE;
      float4 wr[6][2];
#pragma unroll
      for (int kw = 0; kw < 6; ++kw) {
        wr[kw][0] = *reinterpret_cast<const float4*>(wp + (size_t)kw * WSTRIDE);
        wr[kw][1] = *reinterpret_cast<const float4*>(wp + (size_t)kw * WSTRIDE + 4);
      }
      // ---- consume: 6 kw x BJ1 x 8 FMAs
#pragma unroll
      for (int kw = 0; kw < 6; ++kw) {
#pragma unroll
        for (int j = 0; j < BJ1; ++j) {
          const float xs = xv[j][kw];
          acc[j][0] = fmaf(xs, wr[kw][0].x, acc[j][0]);
          acc[j][1] = fmaf(xs, wr[kw][0].y, acc[j][1]);
          acc[j][2] = fmaf(xs, wr[kw][0].z, acc[j][2]);
          acc[j][3] = fmaf(xs, wr[kw][0].w, acc[j][3]);
          acc[j][4] = fmaf(xs, wr[kw][1].x, acc[j][4]);
          acc[j][5] = fmaf(xs, wr[kw][1].y, acc[j][5]);
          acc[j][6] = fmaf(xs, wr[kw][1].z, acc[j][6]);
          acc[j][7] = fmaf(xs, wr[kw][1].w, acc[j][7]);
        }
      }
    }
  }

#pragma unroll
  for (int j = 0; j < BJ1; ++j) {
    float* op = h1 + ((size_t)(bg + j) * O1) * HW1 + hw;
#pragma unroll
    for (int o = 0; o < O1; ++o) op[(size_t)o * HW1] = fmaxf(acc[j][o], 0.f);
  }
}

// ---- locally-connected layer 2 + ReLU, GEMM-ified per spatial location.
__global__ __launch_bounds__(256) void lc2_kernel(const float* __restrict__ h1,
                                                  const float* __restrict__ w2t,
                                                  const float* __restrict__ b2,
                                                  float* __restrict__ h2) {
  __shared__ float ws[P2 * O2];                 // 18432 B
  const int hw = blockIdx.x;
  const int lane = threadIdx.x & 63;
  const int og = threadIdx.x >> 6;
  const int b = blockIdx.y * 64 + lane;
  const int ho = hw / WO2, wo = hw - ho * WO2;

  for (int i = threadIdx.x; i < P2 * O2; i += 256) {
    const int p = i >> 4, o = i & 15;
    ws[i] = w2t[((size_t)p * HW2 + hw) * O2 + o];
  }
  __syncthreads();

  float acc[4];
#pragma unroll
  for (int oi = 0; oi < 4; ++oi) acc[oi] = b2[(og * 4 + oi) * HW2 + hw];

  const float* xb = h1 + (size_t)b * IMG2 + (size_t)(ho * 4) * W2c + wo * 4;

#pragma unroll 1
  for (int c = 0; c < C2; ++c) {
#pragma unroll
    for (int kh = 0; kh < 6; ++kh) {
      const float* xr = xb + c * PLANE2 + kh * W2c;
      const float2 a0 = *reinterpret_cast<const float2*>(xr);
      const float2 a1 = *reinterpret_cast<const float2*>(xr + 2);
      const float2 a2 = *reinterpret_cast<const float2*>(xr + 4);
      float xvv[6];
      xvv[0] = a0.x; xvv[1] = a0.y; xvv[2] = a1.x;
      xvv[3] = a1.y; xvv[4] = a2.x; xvv[5] = a2.y;
#pragma unroll
      for (int kw = 0; kw < 6; ++kw) {
        const int p = (c * 6 + kh) * 6 + kw;
        const float4 wv = *reinterpret_cast<const float4*>(&ws[p * O2 + og * 4]);
        acc[0] = fmaf(xvv[kw], wv.x, acc[0]);
        acc[1] = fmaf(xvv[kw], wv.y, acc[1]);
        acc[2] = fmaf(xvv[kw], wv.z, acc[2]);
        acc[3] = fmaf(xvv[kw], wv.w, acc[3]);
      }
    }
  }

#pragma unroll
  for (int oi = 0; oi < 4; ++oi) {
    h2[((size_t)b * O2 + og * 4 + oi) * HW2 + hw] = fmaxf(acc[oi], 0.f);
  }
}

// ---- fused head: maxpool(2) -> FC1+ReLU -> FC2 -> softmax.
// one block (512 thr = 8 waves) per batch row; all intermediates in LDS.
__global__ __launch_bounds__(512) void head_kernel(const float* __restrict__ h2,
                                                   const float* __restrict__ fc1w,
                                                   const float* __restrict__ fc1b,
                                                   const float* __restrict__ fc2w,
                                                   const float* __restrict__ fc2b,
                                                   float* __restrict__ out) {
  __shared__ __align__(16) float sp[NPOOL];
  __shared__ __align__(16) float sh[N1];
  __shared__ float sl[N2];
  __shared__ float red[2];
  const int b = blockIdx.x;
  const int tid = threadIdx.x;

  if (tid < NPOOL) {
    const int o = tid / 30, r2 = tid - o * 30;
    const int i = r2 / 5, j = r2 - i * 5;
    const float* base = h2 + ((size_t)(b * O2 + o) * HO2 + 2 * i) * WO2 + 2 * j;
    sp[tid] = fmaxf(fmaxf(base[0], base[1]), fmaxf(base[WO2], base[WO2 + 1]));
  }
  __syncthreads();

  const int wv = tid >> 6, ln = tid & 63;
  const float4* sp4 = reinterpret_cast<const float4*>(sp);
  for (int n = wv; n < N1; n += 8) {
    const float4* wr = reinterpret_cast<const float4*>(fc1w + (size_t)n * NPOOL);
    float4 a = wr[ln], p = sp4[ln];
    float s = fmaf(a.x, p.x, fmaf(a.y, p.y, fmaf(a.z, p.z, a.w * p.w)));
    if (ln < 56) {
      float4 a2 = wr[64 + ln], p2 = sp4[64 + ln];
      s = fmaf(a2.x, p2.x, fmaf(a2.y, p2.y, fmaf(a2.z, p2.z, fmaf(a2.w, p2.w, s))));
    }
#pragma unroll
    for (int off = 32; off > 0; off >>= 1) s += __shfl_xor(s, off, 64);
    if (ln == 0) sh[n] = fmaxf(s + fc1b[n], 0.f);
  }
  __syncthreads();

  const float4* sh4 = reinterpret_cast<const float4*>(sh);
  for (int n = wv; n < N2; n += 8) {
    const float4* wr = reinterpret_cast<const float4*>(fc2w + (size_t)n * N1);
    float4 a = wr[ln], p = sh4[ln];
    float s = fmaf(a.x, p.x, fmaf(a.y, p.y, fmaf(a.z, p.z, a.w * p.w)));
    if (ln < 11) {
      float4 a2 = wr[64 + ln], p2 = sh4[64 + ln];
      s = fmaf(a2.x, p2.x, fmaf(a2.y, p2.y, fmaf(a2.z, p2.z, fmaf(a2.w, p2.w, s))));
    }
#pragma unroll
    for (int off = 32; off > 0; off >>= 1) s += __shfl_xor(s, off, 64);
    if (ln == 0) sl[n] = s + fc2b[n];
  }
  __syncthreads();

  if (wv == 0) {
    float m = fmaxf(fmaxf(sl[ln], sl[ln + 64]), sl[ln + 128]);
    if (ln < 8) m = fmaxf(m, sl[192 + ln]);
#pragma unroll
    for (int off = 32; off > 0; off >>= 1) m = fmaxf(m, __shfl_xor(m, off, 64));
    if (ln == 0) red[0] = m;
  }
  __syncthreads();
  const float mx = red[0];
  if (tid < N2) sl[tid] = expf(sl[tid] - mx);
  __syncthreads();
  if (wv == 0) {
    float s = sl[ln] + sl[ln + 64] + sl[ln + 128] + (ln < 8 ? sl[192 + ln] : 0.f);
#pragma unroll
    for (int off = 32; off > 0; off >>= 1) s += __shfl_xor(s, off, 64);
    if (ln == 0) red[1] = s;
  }
  __syncthreads();
  if (tid < N2) out[(size_t)b * N2 + tid] = sl[tid] / red[1];
}

}  // namespace

extern "C" void kernel_launch(void* const* d_in, const int* in_sizes, int n_in,
                              void* d_out, int out_size, void* d_ws, size_t ws_size,
                              hipStream_t stream) {
  const float* x     = (const float*)d_in[0];
  const float* w1    = (const float*)d_in[1];
  const float* b1    = (const float*)d_in[2];
  const float* w2    = (const float*)d_in[3];
  const float* b2    = (const float*)d_in[4];
  const float* fc1_w = (const float*)d_in[5];
  const float* fc1_b = (const float*)d_in[6];
  const float* fc2_w = (const float*)d_in[7];
  const float* fc2_b = (const float*)d_in[8];
  float* out = (float*)d_out;

  float* ws  = (float*)d_ws;
  float* w1t = ws;                                  // 2,052,864 f
  float* w2t = w1t + (size_t)O1 * P1 * HW1;         //   599,040 f
  float* h1  = w2t + (size_t)O2 * P2 * HW2;         // 4,866,048 f
  float* h2  = h1 + (size_t)BATCH * O1 * HW1;       //   532,480 f

  wt1_kernel<<<(P1 * HW1 + 255) / 256, 256, 0, stream>>>(w1, w1t);
  wt2_kernel<<<(P2 * HW2 + 255) / 256, 256, 0, stream>>>(w2, w2t);
  lc1_kernel<<<dim3((HW1 + 63) / 64, BATCH / BPB1), 256, 0, stream>>>(x, w1t, b1, h1);
  lc2_kernel<<<dim3(HW2, 4), 256, 0, stream>>>(h1, w2t, b2, h2);
  head_kernel<<<BATCH, 512, 0, stream>>>(h2, fc1_w, fc1_b, fc2_w, fc2_b, out);
}

// Round 6
// 190.815 us; speedup vs baseline: 2.1281x; 1.0016x over previous
//
#include <hip/hip_runtime.h>
#include <cmath>

namespace {

constexpr int BATCH = 256;
// layer 1
constexpr int C1 = 3, H1 = 218, W1 = 178;
constexpr int IMG1 = C1 * H1 * W1;            // 116412
constexpr int PLANE1 = H1 * W1;               // 38804
constexpr int O1 = 8, HO1 = 54, WO1 = 44;
constexpr int HW1 = HO1 * WO1;                // 2376
constexpr int P1 = C1 * 36;                   // 108
// layer 2
constexpr int C2 = 8, H2c = 54, W2c = 44;
constexpr int IMG2 = C2 * H2c * W2c;          // 19008
constexpr int PLANE2 = H2c * W2c;             // 2376
constexpr int O2 = 16, HO2 = 13, WO2 = 10;
constexpr int HW2 = HO2 * WO2;                // 130
constexpr int P2 = C2 * 36;                   // 288
// head
constexpr int NPOOL = 480;                    // 16*6*5
constexpr int N1 = 300, N2 = 200;

// lc1 blocking: 4 waves/block, each wave = 2 batches; block covers 64 hw.
constexpr int BJ1 = 2;
constexpr int BPB1 = 4 * BJ1;                 // 8 batches per block

// ---- transpose w1 (O1,P1,HW1) -> (P1*HW1, O1)
__global__ __launch_bounds__(256) void wt1_kernel(const float* __restrict__ w,
                                                  float* __restrict__ wt) {
  const int idx = blockIdx.x * 256 + threadIdx.x;   // p*HW1 + hw
  if (idx >= P1 * HW1) return;
  float v[O1];
#pragma unroll
  for (int o = 0; o < O1; ++o) v[o] = w[(size_t)o * (P1 * HW1) + idx];
  float4* dst = reinterpret_cast<float4*>(wt + (size_t)idx * O1);
  dst[0] = make_float4(v[0], v[1], v[2], v[3]);
  dst[1] = make_float4(v[4], v[5], v[6], v[7]);
}

// ---- transpose w2 (O2,P2,HW2) -> (P2*HW2, O2)
__global__ __launch_bounds__(256) void wt2_kernel(const float* __restrict__ w,
                                                  float* __restrict__ wt) {
  const int idx = blockIdx.x * 256 + threadIdx.x;   // p*HW2 + hw
  if (idx >= P2 * HW2) return;
  float v[O2];
#pragma unroll
  for (int o = 0; o < O2; ++o) v[o] = w[(size_t)o * (P2 * HW2) + idx];
  float4* dst = reinterpret_cast<float4*>(wt + (size_t)idx * O2);
  dst[0] = make_float4(v[0], v[1], v[2], v[3]);
  dst[1] = make_float4(v[4], v[5], v[6], v[7]);
  dst[2] = make_float4(v[8], v[9], v[10], v[11]);
  dst[3] = make_float4(v[12], v[13], v[14], v[15]);
}

// ---- locally-connected layer 1 + ReLU
// 256 thr = 64 hw-lanes x 4 waves (wave = 2 batches); grid (38, 32).
// __launch_bounds__(256, 2): VGPR cap 128. Round-5 evidence: without the
// hint the allocator picks 32 VGPRs and serializes all 324 VMEM per wave
// (~790 cy each, VALUBusy 9%). Round-4 evidence: (256,2) does allocate 128;
// its spill came from BJ1=4's live set (48 xv/xn + 32 acc + 48 wr > 128).
// Here live set ~90 regs (12 xv + 16 acc + 48 wr + addr) -> fits, and the
// scheduler can cluster the 18 independent loads per (c,kh) body.
__global__ __launch_bounds__(256, 2) void lc1_kernel(const float* __restrict__ x,
                                                     const float* __restrict__ w1t,
                                                     const float* __restrict__ b1,
                                                     float* __restrict__ h1) {
  const int lane = threadIdx.x & 63;
  const int wave = threadIdx.x >> 6;
  const int hw = blockIdx.x * 64 + lane;
  if (hw >= HW1) return;
  const int bg = blockIdx.y * BPB1 + wave * BJ1;
  const int ho = hw / WO1, wo = hw - ho * WO1;

  float acc[BJ1][O1];
#pragma unroll
  for (int o = 0; o < O1; ++o) {
    const float bv = b1[o * HW1 + hw];
#pragma unroll
    for (int j = 0; j < BJ1; ++j) acc[j][o] = bv;
  }

  const float* xbase = x + (size_t)bg * IMG1 + (size_t)(ho * 4) * W1 + wo * 4;
  const float* wbase = w1t + (size_t)hw * O1;
  constexpr size_t WSTRIDE = (size_t)HW1 * O1;      // floats between consecutive p

#pragma unroll 1
  for (int c = 0; c < C1; ++c) {
#pragma unroll
    for (int kh = 0; kh < 6; ++kh) {
      // ---- issue x loads (6 VMEM, independent)
      float xv[BJ1][6];
#pragma unroll
      for (int j = 0; j < BJ1; ++j) {
        const float* xr = xbase + (size_t)j * IMG1 + (size_t)c * PLANE1 + (size_t)kh * W1;
        const float2 a0 = *reinterpret_cast<const float2*>(xr);
        const float2 a1 = *reinterpret_cast<const float2*>(xr + 2);
        const float2 a2 = *reinterpret_cast<const float2*>(xr + 4);
        xv[j][0] = a0.x; xv[j][1] = a0.y;
        xv[j][2] = a1.x; xv[j][3] = a1.y;
        xv[j][4] = a2.x; xv[j][5] = a2.y;
      }
      // ---- issue ALL 12 w loads for this (c,kh) (independent, named regs)
      const float* wp = wbase + (size_t)((c * 6 + kh) * 6) * WSTRIDE;
      float4 wr[6][2];
#pragma unroll
      for (int kw = 0; kw < 6; ++kw) {
        wr[kw][0] = *reinterpret_cast<const float4*>(wp + (size_t)kw * WSTRIDE);
        wr[kw][1] = *reinterpret_cast<const float4*>(wp + (size_t)kw * WSTRIDE + 4);
      }
      // ---- consume: 6 kw x BJ1 x 8 FMAs
#pragma unroll
      for (int kw = 0; kw < 6; ++kw) {
#pragma unroll
        for (int j = 0; j < BJ1; ++j) {
          const float xs = xv[j][kw];
          acc[j][0] = fmaf(xs, wr[kw][0].x, acc[j][0]);
          acc[j][1] = fmaf(xs, wr[kw][0].y, acc[j][1]);
          acc[j][2] = fmaf(xs, wr[kw][0].z, acc[j][2]);
          acc[j][3] = fmaf(xs, wr[kw][0].w, acc[j][3]);
          acc[j][4] = fmaf(xs, wr[kw][1].x, acc[j][4]);
          acc[j][5] = fmaf(xs, wr[kw][1].y, acc[j][5]);
          acc[j][6] = fmaf(xs, wr[kw][1].z, acc[j][6]);
          acc[j][7] = fmaf(xs, wr[kw][1].w, acc[j][7]);
        }
      }
    }
  }

#pragma unroll
  for (int j = 0; j < BJ1; ++j) {
    float* op = h1 + ((size_t)(bg + j) * O1) * HW1 + hw;
#pragma unroll
    for (int o = 0; o < O1; ++o) op[(size_t)o * HW1] = fmaxf(acc[j][o], 0.f);
  }
}

// ---- locally-connected layer 2 + ReLU, GEMM-ified per spatial location.
__global__ __launch_bounds__(256) void lc2_kernel(const float* __restrict__ h1,
                                                  const float* __restrict__ w2t,
                                                  const float* __restrict__ b2,
                                                  float* __restrict__ h2) {
  __shared__ float ws[P2 * O2];                 // 18432 B
  const int hw = blockIdx.x;
  const int lane = threadIdx.x & 63;
  const int og = threadIdx.x >> 6;
  const int b = blockIdx.y * 64 + lane;
  const int ho = hw / WO2, wo = hw - ho * WO2;

  for (int i = threadIdx.x; i < P2 * O2; i += 256) {
    const int p = i >> 4, o = i & 15;
    ws[i] = w2t[((size_t)p * HW2 + hw) * O2 + o];
  }
  __syncthreads();

  float acc[4];
#pragma unroll
  for (int oi = 0; oi < 4; ++oi) acc[oi] = b2[(og * 4 + oi) * HW2 + hw];

  const float* xb = h1 + (size_t)b * IMG2 + (size_t)(ho * 4) * W2c + wo * 4;

#pragma unroll 1
  for (int c = 0; c < C2; ++c) {
#pragma unroll
    for (int kh = 0; kh < 6; ++kh) {
      const float* xr = xb + c * PLANE2 + kh * W2c;
      const float2 a0 = *reinterpret_cast<const float2*>(xr);
      const float2 a1 = *reinterpret_cast<const float2*>(xr + 2);
      const float2 a2 = *reinterpret_cast<const float2*>(xr + 4);
      float xvv[6];
      xvv[0] = a0.x; xvv[1] = a0.y; xvv[2] = a1.x;
      xvv[3] = a1.y; xvv[4] = a2.x; xvv[5] = a2.y;
#pragma unroll
      for (int kw = 0; kw < 6; ++kw) {
        const int p = (c * 6 + kh) * 6 + kw;
        const float4 wv = *reinterpret_cast<const float4*>(&ws[p * O2 + og * 4]);
        acc[0] = fmaf(xvv[kw], wv.x, acc[0]);
        acc[1] = fmaf(xvv[kw], wv.y, acc[1]);
        acc[2] = fmaf(xvv[kw], wv.z, acc[2]);
        acc[3] = fmaf(xvv[kw], wv.w, acc[3]);
      }
    }
  }

#pragma unroll
  for (int oi = 0; oi < 4; ++oi) {
    h2[((size_t)b * O2 + og * 4 + oi) * HW2 + hw] = fmaxf(acc[oi], 0.f);
  }
}

// ---- fused head: maxpool(2) -> FC1+ReLU -> FC2 -> softmax.
// one block (512 thr = 8 waves) per batch row; all intermediates in LDS.
__global__ __launch_bounds__(512) void head_kernel(const float* __restrict__ h2,
                                                   const float* __restrict__ fc1w,
                                                   const float* __restrict__ fc1b,
                                                   const float* __restrict__ fc2w,
                                                   const float* __restrict__ fc2b,
                                                   float* __restrict__ out) {
  __shared__ __align__(16) float sp[NPOOL];
  __shared__ __align__(16) float sh[N1];
  __shared__ float sl[N2];
  __shared__ float red[2];
  const int b = blockIdx.x;
  const int tid = threadIdx.x;

  if (tid < NPOOL) {
    const int o = tid / 30, r2 = tid - o * 30;
    const int i = r2 / 5, j = r2 - i * 5;
    const float* base = h2 + ((size_t)(b * O2 + o) * HO2 + 2 * i) * WO2 + 2 * j;
    sp[tid] = fmaxf(fmaxf(base[0], base[1]), fmaxf(base[WO2], base[WO2 + 1]));
  }
  __syncthreads();

  const int wv = tid >> 6, ln = tid & 63;
  const float4* sp4 = reinterpret_cast<const float4*>(sp);
  for (int n = wv; n < N1; n += 8) {
    const float4* wr = reinterpret_cast<const float4*>(fc1w + (size_t)n * NPOOL);
    float4 a = wr[ln], p = sp4[ln];
    float s = fmaf(a.x, p.x, fmaf(a.y, p.y, fmaf(a.z, p.z, a.w * p.w)));
    if (ln < 56) {
      float4 a2 = wr[64 + ln], p2 = sp4[64 + ln];
      s = fmaf(a2.x, p2.x, fmaf(a2.y, p2.y, fmaf(a2.z, p2.z, fmaf(a2.w, p2.w, s))));
    }
#pragma unroll
    for (int off = 32; off > 0; off >>= 1) s += __shfl_xor(s, off, 64);
    if (ln == 0) sh[n] = fmaxf(s + fc1b[n], 0.f);
  }
  __syncthreads();

  const float4* sh4 = reinterpret_cast<const float4*>(sh);
  for (int n = wv; n < N2; n += 8) {
    const float4* wr = reinterpret_cast<const float4*>(fc2w + (size_t)n * N1);
    float4 a = wr[ln], p = sh4[ln];
    float s = fmaf(a.x, p.x, fmaf(a.y, p.y, fmaf(a.z, p.z, a.w * p.w)));
    if (ln < 11) {
      float4 a2 = wr[64 + ln], p2 = sh4[64 + ln];
      s = fmaf(a2.x, p2.x, fmaf(a2.y, p2.y, fmaf(a2.z, p2.z, fmaf(a2.w, p2.w, s))));
    }
#pragma unroll
    for (int off = 32; off > 0; off >>= 1) s += __shfl_xor(s, off, 64);
    if (ln == 0) sl[n] = s + fc2b[n];
  }
  __syncthreads();

  if (wv == 0) {
    float m = fmaxf(fmaxf(sl[ln], sl[ln + 64]), sl[ln + 128]);
    if (ln < 8) m = fmaxf(m, sl[192 + ln]);
#pragma unroll
    for (int off = 32; off > 0; off >>= 1) m = fmaxf(m, __shfl_xor(m, off, 64));
    if (ln == 0) red[0] = m;
  }
  __syncthreads();
  const float mx = red[0];
  if (tid < N2) sl[tid] = expf(sl[tid] - mx);
  __syncthreads();
  if (wv == 0) {
    float s = sl[ln] + sl[ln + 64] + sl[ln + 128] + (ln < 8 ? sl[192 + ln] : 0.f);
#pragma unroll
    for (int off = 32; off > 0; off >>= 1) s += __shfl_xor(s, off, 64);
    if (ln == 0) red[1] = s;
  }
  __syncthreads();
  if (tid < N2) out[(size_t)b * N2 + tid] = sl[tid] / red[1];
}

}  // namespace

extern "C" void kernel_launch(void* const* d_in, const int* in_sizes, int n_in,
                              void* d_out, int out_size, void* d_ws, size_t ws_size,
                              hipStream_t stream) {
  const float* x     = (const float*)d_in[0];
  const float* w1    = (const float*)d_in[1];
  const float* b1    = (const float*)d_in[2];
  const float* w2    = (const float*)d_in[3];
  const float* b2    = (const float*)d_in[4];
  const float* fc1_w = (const float*)d_in[5];
  const float* fc1_b = (const float*)d_in[6];
  const float* fc2_w = (const float*)d_in[7];
  const float* fc2_b = (const float*)d_in[8];
  float* out = (float*)d_out;

  float* ws  = (float*)d_ws;
  float* w1t = ws;                                  // 2,052,864 f
  float* w2t = w1t + (size_t)O1 * P1 * HW1;         //   599,040 f
  float* h1  = w2t + (size_t)O2 * P2 * HW2;         // 4,866,048 f
  float* h2  = h1 + (size_t)BATCH * O1 * HW1;       //   532,480 f

  wt1_kernel<<<(P1 * HW1 + 255) / 256, 256, 0, stream>>>(w1, w1t);
  wt2_kernel<<<(P2 * HW2 + 255) / 256, 256, 0, stream>>>(w2, w2t);
  lc1_kernel<<<dim3((HW1 + 63) / 64, BATCH / BPB1), 256, 0, stream>>>(x, w1t, b1, h1);
  lc2_kernel<<<dim3(HW2, 4), 256, 0, stream>>>(h1, w2t, b2, h2);
  head_kernel<<<BATCH, 512, 0, stream>>>(h2, fc1_w, fc1_b, fc2_w, fc2_b, out);
}

// Round 7
// 183.131 us; speedup vs baseline: 2.2174x; 1.0420x over previous
//
#include <hip/hip_runtime.h>
#include <cmath>

namespace {

constexpr int BATCH = 256;
// layer 1
constexpr int C1 = 3, H1 = 218, W1 = 178;
constexpr int IMG1 = C1 * H1 * W1;            // 116412
constexpr int PLANE1 = H1 * W1;               // 38804
constexpr int O1 = 8, HO1 = 54, WO1 = 44;
constexpr int HW1 = HO1 * WO1;                // 2376
constexpr int P1 = C1 * 36;                   // 108
// layer 2
constexpr int C2 = 8, H2c = 54, W2c = 44;
constexpr int IMG2 = C2 * H2c * W2c;          // 19008
constexpr int PLANE2 = H2c * W2c;             // 2376
constexpr int O2 = 16, HO2 = 13, WO2 = 10;
constexpr int HW2 = HO2 * WO2;                // 130
constexpr int P2 = C2 * 36;                   // 288
// head
constexpr int NPOOL = 480;                    // 16*6*5
constexpr int N1 = 300, N2 = 200;

// lc1 blocking: 4 waves/block, each wave = 2 batches; block covers 64 hw.
constexpr int BJ1 = 2;
constexpr int BPB1 = 4 * BJ1;                 // 8 batches per block

// ---- transpose w1 (O1,P1,HW1) -> (P1*HW1, O1)
__global__ __launch_bounds__(256) void wt1_kernel(const float* __restrict__ w,
                                                  float* __restrict__ wt) {
  const int idx = blockIdx.x * 256 + threadIdx.x;   // p*HW1 + hw
  if (idx >= P1 * HW1) return;
  float v[O1];
#pragma unroll
  for (int o = 0; o < O1; ++o) v[o] = w[(size_t)o * (P1 * HW1) + idx];
  float4* dst = reinterpret_cast<float4*>(wt + (size_t)idx * O1);
  dst[0] = make_float4(v[0], v[1], v[2], v[3]);
  dst[1] = make_float4(v[4], v[5], v[6], v[7]);
}

// ---- transpose w2 (O2,P2,HW2) -> (P2*HW2, O2)
__global__ __launch_bounds__(256) void wt2_kernel(const float* __restrict__ w,
                                                  float* __restrict__ wt) {
  const int idx = blockIdx.x * 256 + threadIdx.x;   // p*HW2 + hw
  if (idx >= P2 * HW2) return;
  float v[O2];
#pragma unroll
  for (int o = 0; o < O2; ++o) v[o] = w[(size_t)o * (P2 * HW2) + idx];
  float4* dst = reinterpret_cast<float4*>(wt + (size_t)idx * O2);
  dst[0] = make_float4(v[0], v[1], v[2], v[3]);
  dst[1] = make_float4(v[4], v[5], v[6], v[7]);
  dst[2] = make_float4(v[8], v[9], v[10], v[11]);
  dst[3] = make_float4(v[12], v[13], v[14], v[15]);
}

// ---- locally-connected layer 1 + ReLU
// 256 thr = 64 hw-lanes x 4 waves (wave = 2 batches); grid (38, 32).
// MLP fix via hard fence: all 18 VMEM of a (c,kh) body are issued above a
// __builtin_amdgcn_sched_barrier(0); the scheduler cannot sink them to their
// uses (rounds 3/5/6 evidence: without a fence hipcc allocates 32 VGPRs and
// serializes 324 loads x ~790cy = the whole 108 us). Live set ~90 VGPR.
__global__ __launch_bounds__(256) void lc1_kernel(const float* __restrict__ x,
                                                  const float* __restrict__ w1t,
                                                  const float* __restrict__ b1,
                                                  float* __restrict__ h1) {
  const int lane = threadIdx.x & 63;
  const int wave = threadIdx.x >> 6;
  const int hw = blockIdx.x * 64 + lane;
  if (hw >= HW1) return;
  const int bg = blockIdx.y * BPB1 + wave * BJ1;
  const int ho = hw / WO1, wo = hw - ho * WO1;

  float acc[BJ1][O1];
#pragma unroll
  for (int o = 0; o < O1; ++o) {
    const float bv = b1[o * HW1 + hw];
#pragma unroll
    for (int j = 0; j < BJ1; ++j) acc[j][o] = bv;
  }

  const float* xbase = x + (size_t)bg * IMG1 + (size_t)(ho * 4) * W1 + wo * 4;
  const float* wbase = w1t + (size_t)hw * O1;
  constexpr size_t WSTRIDE = (size_t)HW1 * O1;      // floats between consecutive p

#pragma unroll 1
  for (int c = 0; c < C1; ++c) {
#pragma unroll
    for (int kh = 0; kh < 6; ++kh) {
      // ---- issue x loads (6 VMEM, independent)
      float xv[BJ1][6];
#pragma unroll
      for (int j = 0; j < BJ1; ++j) {
        const float* xr = xbase + (size_t)j * IMG1 + (size_t)c * PLANE1 + (size_t)kh * W1;
        const float2 a0 = *reinterpret_cast<const float2*>(xr);
        const float2 a1 = *reinterpret_cast<const float2*>(xr + 2);
        const float2 a2 = *reinterpret_cast<const float2*>(xr + 4);
        xv[j][0] = a0.x; xv[j][1] = a0.y;
        xv[j][2] = a1.x; xv[j][3] = a1.y;
        xv[j][4] = a2.x; xv[j][5] = a2.y;
      }
      // ---- issue ALL 12 w loads for this (c,kh)
      const float* wp = wbase + (size_t)((c * 6 + kh) * 6) * WSTRIDE;
      float4 wr[6][2];
#pragma unroll
      for (int kw = 0; kw < 6; ++kw) {
        wr[kw][0] = *reinterpret_cast<const float4*>(wp + (size_t)kw * WSTRIDE);
        wr[kw][1] = *reinterpret_cast<const float4*>(wp + (size_t)kw * WSTRIDE + 4);
      }
      // ---- hard fence: loads stay above, FMAs stay below
      __builtin_amdgcn_sched_barrier(0);
      // ---- consume: 6 kw x BJ1 x 8 FMAs
#pragma unroll
      for (int kw = 0; kw < 6; ++kw) {
#pragma unroll
        for (int j = 0; j < BJ1; ++j) {
          const float xs = xv[j][kw];
          acc[j][0] = fmaf(xs, wr[kw][0].x, acc[j][0]);
          acc[j][1] = fmaf(xs, wr[kw][0].y, acc[j][1]);
          acc[j][2] = fmaf(xs, wr[kw][0].z, acc[j][2]);
          acc[j][3] = fmaf(xs, wr[kw][0].w, acc[j][3]);
          acc[j][4] = fmaf(xs, wr[kw][1].x, acc[j][4]);
          acc[j][5] = fmaf(xs, wr[kw][1].y, acc[j][5]);
          acc[j][6] = fmaf(xs, wr[kw][1].z, acc[j][6]);
          acc[j][7] = fmaf(xs, wr[kw][1].w, acc[j][7]);
        }
      }
    }
  }

#pragma unroll
  for (int j = 0; j < BJ1; ++j) {
    float* op = h1 + ((size_t)(bg + j) * O1) * HW1 + hw;
#pragma unroll
    for (int o = 0; o < O1; ++o) op[(size_t)o * HW1] = fmaxf(acc[j][o], 0.f);
  }
}

// ---- locally-connected layer 2 + ReLU, GEMM-ified per spatial location.
// Same load-batch + fence treatment: per c, all 18 x loads issued above a
// sched_barrier(0), then 36 LDS-broadcast reads + 144 FMAs below.
__global__ __launch_bounds__(256) void lc2_kernel(const float* __restrict__ h1,
                                                  const float* __restrict__ w2t,
                                                  const float* __restrict__ b2,
                                                  float* __restrict__ h2) {
  __shared__ float ws[P2 * O2];                 // 18432 B
  const int hw = blockIdx.x;
  const int lane = threadIdx.x & 63;
  const int og = threadIdx.x >> 6;
  const int b = blockIdx.y * 64 + lane;
  const int ho = hw / WO2, wo = hw - ho * WO2;

  for (int i = threadIdx.x; i < P2 * O2; i += 256) {
    const int p = i >> 4, o = i & 15;
    ws[i] = w2t[((size_t)p * HW2 + hw) * O2 + o];
  }
  __syncthreads();

  float acc[4];
#pragma unroll
  for (int oi = 0; oi < 4; ++oi) acc[oi] = b2[(og * 4 + oi) * HW2 + hw];

  const float* xb = h1 + (size_t)b * IMG2 + (size_t)(ho * 4) * W2c + wo * 4;

#pragma unroll 1
  for (int c = 0; c < C2; ++c) {
    // ---- issue all 18 x loads for this c (6 kh x 3 float2)
    float xv[6][6];
#pragma unroll
    for (int kh = 0; kh < 6; ++kh) {
      const float* xr = xb + c * PLANE2 + kh * W2c;
      const float2 a0 = *reinterpret_cast<const float2*>(xr);
      const float2 a1 = *reinterpret_cast<const float2*>(xr + 2);
      const float2 a2 = *reinterpret_cast<const float2*>(xr + 4);
      xv[kh][0] = a0.x; xv[kh][1] = a0.y;
      xv[kh][2] = a1.x; xv[kh][3] = a1.y;
      xv[kh][4] = a2.x; xv[kh][5] = a2.y;
    }
    __builtin_amdgcn_sched_barrier(0);
    // ---- consume from LDS weights
#pragma unroll
    for (int kh = 0; kh < 6; ++kh) {
#pragma unroll
      for (int kw = 0; kw < 6; ++kw) {
        const int p = (c * 6 + kh) * 6 + kw;
        const float4 wv = *reinterpret_cast<const float4*>(&ws[p * O2 + og * 4]);
        acc[0] = fmaf(xv[kh][kw], wv.x, acc[0]);
        acc[1] = fmaf(xv[kh][kw], wv.y, acc[1]);
        acc[2] = fmaf(xv[kh][kw], wv.z, acc[2]);
        acc[3] = fmaf(xv[kh][kw], wv.w, acc[3]);
      }
    }
  }

#pragma unroll
  for (int oi = 0; oi < 4; ++oi) {
    h2[((size_t)b * O2 + og * 4 + oi) * HW2 + hw] = fmaxf(acc[oi], 0.f);
  }
}

// ---- fused head: maxpool(2) -> FC1+ReLU -> FC2 -> softmax.
// one block (512 thr = 8 waves) per batch row; all intermediates in LDS.
__global__ __launch_bounds__(512) void head_kernel(const float* __restrict__ h2,
                                                   const float* __restrict__ fc1w,
                                                   const float* __restrict__ fc1b,
                                                   const float* __restrict__ fc2w,
                                                   const float* __restrict__ fc2b,
                                                   float* __restrict__ out) {
  __shared__ __align__(16) float sp[NPOOL];
  __shared__ __align__(16) float sh[N1];
  __shared__ float sl[N2];
  __shared__ float red[2];
  const int b = blockIdx.x;
  const int tid = threadIdx.x;

  if (tid < NPOOL) {
    const int o = tid / 30, r2 = tid - o * 30;
    const int i = r2 / 5, j = r2 - i * 5;
    const float* base = h2 + ((size_t)(b * O2 + o) * HO2 + 2 * i) * WO2 + 2 * j;
    sp[tid] = fmaxf(fmaxf(base[0], base[1]), fmaxf(base[WO2], base[WO2 + 1]));
  }
  __syncthreads();

  const int wv = tid >> 6, ln = tid & 63;
  const float4* sp4 = reinterpret_cast<const float4*>(sp);
  for (int n = wv; n < N1; n += 8) {
    const float4* wr = reinterpret_cast<const float4*>(fc1w + (size_t)n * NPOOL);
    float4 a = wr[ln], p = sp4[ln];
    float s = fmaf(a.x, p.x, fmaf(a.y, p.y, fmaf(a.z, p.z, a.w * p.w)));
    if (ln < 56) {
      float4 a2 = wr[64 + ln], p2 = sp4[64 + ln];
      s = fmaf(a2.x, p2.x, fmaf(a2.y, p2.y, fmaf(a2.z, p2.z, fmaf(a2.w, p2.w, s))));
    }
#pragma unroll
    for (int off = 32; off > 0; off >>= 1) s += __shfl_xor(s, off, 64);
    if (ln == 0) sh[n] = fmaxf(s + fc1b[n], 0.f);
  }
  __syncthreads();

  const float4* sh4 = reinterpret_cast<const float4*>(sh);
  for (int n = wv; n < N2; n += 8) {
    const float4* wr = reinterpret_cast<const float4*>(fc2w + (size_t)n * N1);
    float4 a = wr[ln], p = sh4[ln];
    float s = fmaf(a.x, p.x, fmaf(a.y, p.y, fmaf(a.z, p.z, a.w * p.w)));
    if (ln < 11) {
      float4 a2 = wr[64 + ln], p2 = sh4[64 + ln];
      s = fmaf(a2.x, p2.x, fmaf(a2.y, p2.y, fmaf(a2.z, p2.z, fmaf(a2.w, p2.w, s))));
    }
#pragma unroll
    for (int off = 32; off > 0; off >>= 1) s += __shfl_xor(s, off, 64);
    if (ln == 0) sl[n] = s + fc2b[n];
  }
  __syncthreads();

  if (wv == 0) {
    float m = fmaxf(fmaxf(sl[ln], sl[ln + 64]), sl[ln + 128]);
    if (ln < 8) m = fmaxf(m, sl[192 + ln]);
#pragma unroll
    for (int off = 32; off > 0; off >>= 1) m = fmaxf(m, __shfl_xor(m, off, 64));
    if (ln == 0) red[0] = m;
  }
  __syncthreads();
  const float mx = red[0];
  if (tid < N2) sl[tid] = expf(sl[tid] - mx);
  __syncthreads();
  if (wv == 0) {
    float s = sl[ln] + sl[ln + 64] + sl[ln + 128] + (ln < 8 ? sl[192 + ln] : 0.f);
#pragma unroll
    for (int off = 32; off > 0; off >>= 1) s += __shfl_xor(s, off, 64);
    if (ln == 0) red[1] = s;
  }
  __syncthreads();
  if (tid < N2) out[(size_t)b * N2 + tid] = sl[tid] / red[1];
}

}  // namespace

extern "C" void kernel_launch(void* const* d_in, const int* in_sizes, int n_in,
                              void* d_out, int out_size, void* d_ws, size_t ws_size,
                              hipStream_t stream) {
  const float* x     = (const float*)d_in[0];
  const float* w1    = (const float*)d_in[1];
  const float* b1    = (const float*)d_in[2];
  const float* w2    = (const float*)d_in[3];
  const float* b2    = (const float*)d_in[4];
  const float* fc1_w = (const float*)d_in[5];
  const float* fc1_b = (const float*)d_in[6];
  const float* fc2_w = (const float*)d_in[7];
  const float* fc2_b = (const float*)d_in[8];
  float* out = (float*)d_out;

  float* ws  = (float*)d_ws;
  float* w1t = ws;                                  // 2,052,864 f
  float* w2t = w1t + (size_t)O1 * P1 * HW1;         //   599,040 f
  float* h1  = w2t + (size_t)O2 * P2 * HW2;         // 4,866,048 f
  float* h2  = h1 + (size_t)BATCH * O1 * HW1;       //   532,480 f

  wt1_kernel<<<(P1 * HW1 + 255) / 256, 256, 0, stream>>>(w1, w1t);
  wt2_kernel<<<(P2 * HW2 + 255) / 256, 256, 0, stream>>>(w2, w2t);
  lc1_kernel<<<dim3((HW1 + 63) / 64, BATCH / BPB1), 256, 0, stream>>>(x, w1t, b1, h1);
  lc2_kernel<<<dim3(HW2, 4), 256, 0, stream>>>(h1, w2t, b2, h2);
  head_kernel<<<BATCH, 512, 0, stream>>>(h2, fc1_w, fc1_b, fc2_w, fc2_b, out);
}